// Round 1
// baseline (445.524 us; speedup 1.0000x reference)
//
#include <hip/hip_runtime.h>
#include <math.h>

// Problem constants (B=2, N=512, C=64, H=8)
constexpr int BDIM = 512;
constexpr int NDIM = 512;
constexpr int CDIM = 64;
constexpr int HDIM = 8;
constexpr int NWAVE = BDIM / 64;
constexpr int RPT   = 32;   // rows per thread

// Coalescing-first decomposition. One block per (b,m).
//   chunk  = t & 3        : which 16 c-values of the row (c-set {j*16+chunk*4+d})
//   head   = (t >> 2) & 7 : which output head (8 lanes duplicate each address ->
//                           coalescer merges to one request + broadcast)
//   rowgrp = t >> 5       : rows [rowgrp*32, rowgrp*32+32)
// Per wave load instruction (fixed j): lanes 0-31 cover ONE full 64B line of one
// row, lanes 32-63 the same line of another row -> 2 dense line-requests/instr
// (vs 64 x 16B sparse requests in the previous thread-per-row layout).
__global__ __launch_bounds__(BDIM, 4)
void mha_kernel(const float* __restrict__ q,
                const float* __restrict__ kk,
                const float* __restrict__ mask,
                const float* __restrict__ W,      // (H, 2C) row-major
                const float* __restrict__ bias,   // (H,)
                float* __restrict__ out)          // (B, N, N, H)
{
    __shared__ float red[NWAVE * HDIM];

    const int bm     = blockIdx.x;      // b*512 + m
    const int t      = threadIdx.x;
    const int chunk  = t & 3;
    const int head   = (t >> 2) & 7;
    const int rowgrp = t >> 5;          // 0..15
    const int row0   = rowgrp << 5;

    // Per-thread W fragment: 16 q-weights + 16 k-weights for this head's c-set.
    // W is 4 KB total -> L1/L2 resident; loaded once per thread.
    float4 wq4[4], wk4[4];
#pragma unroll
    for (int j = 0; j < 4; ++j) {
        wq4[j] = *(const float4*)(W + head * 2 * CDIM + j * 16 + chunk * 4);
        wk4[j] = *(const float4*)(W + head * 2 * CDIM + CDIM + j * 16 + chunk * 4);
    }
    const float bh = bias[head];

    const float* qb = q    + (size_t)bm * NDIM * CDIM;
    const float* kb = kk   + (size_t)bm * NDIM * CDIM;
    const float* mb = mask + (size_t)bm * NDIM;

    float vals[RPT];
    float psum = 0.0f;

#pragma unroll
    for (int k = 0; k < RPT; ++k) {
        const int row = row0 + k;
        const float4* qp = (const float4*)(qb + (size_t)row * CDIM);
        const float4* kp = (const float4*)(kb + (size_t)row * CDIM);

        float s = 0.0f;
#pragma unroll
        for (int j = 0; j < 4; ++j) {
            float4 xq = qp[j * 4 + chunk];      // dense: lane-adjacent = addr-adjacent
            s = fmaf(xq.x, wq4[j].x, s);
            s = fmaf(xq.y, wq4[j].y, s);
            s = fmaf(xq.z, wq4[j].z, s);
            s = fmaf(xq.w, wq4[j].w, s);
        }
#pragma unroll
        for (int j = 0; j < 4; ++j) {
            float4 xk = kp[j * 4 + chunk];
            s = fmaf(xk.x, wk4[j].x, s);
            s = fmaf(xk.y, wk4[j].y, s);
            s = fmaf(xk.z, wk4[j].z, s);
            s = fmaf(xk.w, wk4[j].w, s);
        }
        // complete the 64-c dot across the 4 chunk-lanes (lanes l^1, l^2)
        s += __shfl_xor(s, 1, 64);
        s += __shfl_xor(s, 2, 64);

        const float v = __expf(s + bh) * mb[row];
        vals[k] = v;        // all 4 chunk-lanes hold identical v
        psum += v;
    }

    // Block-wide sum over n (axis=2) for this head.
    // chunk-quad lanes are identical -> *4 is the exact quad-sum.
    float tot = psum * 4.0f;
    tot += __shfl_xor(tot, 32, 64);     // add the wave's other rowgroup
    // every lane now holds 4 * (sum over this wave's 64 rows) for its head

    const int lane = t & 63;
    const int wid  = t >> 6;
    if (lane < 32 && (lane & 3) == 0)
        red[wid * HDIM + (lane >> 2)] = tot;
    __syncthreads();

    float total = 0.0f;
#pragma unroll
    for (int w2 = 0; w2 < NWAVE; ++w2) total += red[w2 * HDIM + head];
    const float rinv = 4.0f / total;    // total = 4 * true block sum

    // Epilogue: head-lanes (chunk==0) write 8 contiguous dwords per row.
    float* ob = out + (size_t)bm * NDIM * HDIM;
    if (chunk == 0) {
#pragma unroll
        for (int k = 0; k < RPT; ++k)
            ob[(size_t)(row0 + k) * HDIM + head] = vals[k] * rinv;
    }
}

extern "C" void kernel_launch(void* const* d_in, const int* in_sizes, int n_in,
                              void* d_out, int out_size, void* d_ws, size_t ws_size,
                              hipStream_t stream) {
    const float* q    = (const float*)d_in[0];
    const float* k    = (const float*)d_in[1];
    const float* mask = (const float*)d_in[2];
    const float* W    = (const float*)d_in[3];
    const float* b    = (const float*)d_in[4];
    float* out = (float*)d_out;

    hipLaunchKernelGGL(mha_kernel, dim3(2 * NDIM), dim3(BDIM), 0, stream,
                       q, k, mask, W, b, out);
}

// Round 2
// 292.698 us; speedup vs baseline: 1.5221x; 1.5221x over previous
//
#include <hip/hip_runtime.h>
#include <math.h>

// Problem constants (B=2, N=512, C=64, H=8)
constexpr int BDIM = 512;
constexpr int NDIM = 512;
constexpr int CDIM = 64;
constexpr int HDIM = 8;
constexpr int NWAVE = BDIM / 64;

// One block per (b,m); thread t owns row n = t (same compute mapping as the
// 112.8us kernel). NEW: global->LDS staging so every global load instruction
// is dense (64 lanes x 16 B covering 16 complete 64B lines), instead of the
// old stride-256B pattern (64 lines touched, 16 B used of each).
//
// Per-wave private tile: 64 rows x 16 floats (one 64B c-slice of each row),
// 4 KB/wave, NO __syncthreads in the hot loop (waves slip independently).
// 8 passes: slice p&3 of {q (p<4), k (p>=4)}; acc[8] accumulates in the same
// c-order as the reference kernel (identical rounding -> same absmax).
//
// LDS swizzle: 16B-chunk index cs = j ^ ((row>>1)&3). Read side: lane=row,
// chunk j: bank-quad = (row&1)*16 + cs*4 -> 8 lane-classes on 8 distinct
// quads = structural minimum 8-way (1 KB per instr / 128 B-per-cycle LDS).
__global__ __launch_bounds__(BDIM, 6)
void mha_kernel(const float* __restrict__ q,
                const float* __restrict__ kk,
                const float* __restrict__ mask,
                const float* __restrict__ W,      // (H, 2C) row-major
                const float* __restrict__ bias,   // (H,)
                float* __restrict__ out)          // (B, N, N, H)
{
    __shared__ float4 tile[NWAVE][64][4];   // 32 KB: per-wave 64 rows x 4 chunks
    __shared__ float red[NWAVE * HDIM];
    __shared__ float rsum_lds[HDIM];

    const int bm   = blockIdx.x;            // b*512 + m
    const int t    = threadIdx.x;
    const int lane = t & 63;
    const int wid  = t >> 6;

    const float* qb = q  + (size_t)bm * NDIM * CDIM;
    const float* kb = kk + (size_t)bm * NDIM * CDIM;

    // staging role: lane loads chunk sj of local rows {srow, srow+16, +32, +48}
    const int srow = lane >> 2;             // 0..15
    const int sj   = lane & 3;              // 0..3

    float acc[HDIM];
#pragma unroll
    for (int h = 0; h < HDIM; ++h) acc[h] = 0.0f;

    const int rsw = (lane >> 1) & 3;        // read-side swizzle for own row

#pragma unroll
    for (int p = 0; p < 8; ++p) {
        const float* src = (p < 4) ? qb : kb;
        const int slice  = p & 3;
        // ---- dense global load: 4 instrs, each = 16 complete 64B lines ----
        const float* srcw = src + (size_t)(wid * 64) * CDIM + slice * 16 + sj * 4;
        float4 g0 = *(const float4*)(srcw + (size_t)(srow +  0) * CDIM);
        float4 g1 = *(const float4*)(srcw + (size_t)(srow + 16) * CDIM);
        float4 g2 = *(const float4*)(srcw + (size_t)(srow + 32) * CDIM);
        float4 g3 = *(const float4*)(srcw + (size_t)(srow + 48) * CDIM);
        // ---- swizzled LDS write (8-way = structural min) ----
        {
            const int r0 = srow,      c0 = sj ^ ((r0 >> 1) & 3);
            const int r1 = srow + 16, c1 = sj ^ ((r1 >> 1) & 3);
            const int r2 = srow + 32, c2 = sj ^ ((r2 >> 1) & 3);
            const int r3 = srow + 48, c3 = sj ^ ((r3 >> 1) & 3);
            tile[wid][r0][c0] = g0;
            tile[wid][r1][c1] = g1;
            tile[wid][r2][c2] = g2;
            tile[wid][r3][c3] = g3;
        }
        // ---- each lane reads its own row's 64B slice (swizzled) ----
        float4 x0 = tile[wid][lane][0 ^ rsw];
        float4 x1 = tile[wid][lane][1 ^ rsw];
        float4 x2 = tile[wid][lane][2 ^ rsw];
        float4 x3 = tile[wid][lane][3 ^ rsw];
        // ---- FMA with SGPR-resident W (wave-uniform address) ----
        const float* wbase = W + (p >= 4 ? CDIM : 0) + slice * 16;
#pragma unroll
        for (int h = 0; h < HDIM; ++h) {
            const float* wh = wbase + h * 2 * CDIM;
            float a = acc[h];
            a = fmaf(x0.x, wh[0],  a); a = fmaf(x0.y, wh[1],  a);
            a = fmaf(x0.z, wh[2],  a); a = fmaf(x0.w, wh[3],  a);
            a = fmaf(x1.x, wh[4],  a); a = fmaf(x1.y, wh[5],  a);
            a = fmaf(x1.z, wh[6],  a); a = fmaf(x1.w, wh[7],  a);
            a = fmaf(x2.x, wh[8],  a); a = fmaf(x2.y, wh[9],  a);
            a = fmaf(x2.z, wh[10], a); a = fmaf(x2.w, wh[11], a);
            a = fmaf(x3.x, wh[12], a); a = fmaf(x3.y, wh[13], a);
            a = fmaf(x3.z, wh[14], a); a = fmaf(x3.w, wh[15], a);
            acc[h] = a;
        }
    }

    const float mval = mask[bm * NDIM + t];
    float val[HDIM];
    float psum[HDIM];
#pragma unroll
    for (int h = 0; h < HDIM; ++h) {
        float v = __expf(acc[h] + bias[h]) * mval;
        val[h]  = v;
        psum[h] = v;
    }

    // block-wide sum over n (axis=2): wave butterfly, then cross-wave via LDS
#pragma unroll
    for (int h = 0; h < HDIM; ++h) {
        float s = psum[h];
#pragma unroll
        for (int off = 32; off >= 1; off >>= 1)
            s += __shfl_xor(s, off, 64);
        psum[h] = s;
    }
    if (lane == 0) {
#pragma unroll
        for (int h = 0; h < HDIM; ++h) red[wid * HDIM + h] = psum[h];
    }
    __syncthreads();
    if (t < HDIM) {
        float s = 0.0f;
#pragma unroll
        for (int w = 0; w < NWAVE; ++w) s += red[w * HDIM + t];
        rsum_lds[t] = 1.0f / s;
    }
    __syncthreads();

    float rs[HDIM];
#pragma unroll
    for (int h = 0; h < HDIM; ++h) rs[h] = rsum_lds[h];

    float* orow = out + (size_t)bm * NDIM * HDIM;
    float4 lo = make_float4(val[0] * rs[0], val[1] * rs[1],
                            val[2] * rs[2], val[3] * rs[3]);
    float4 hi = make_float4(val[4] * rs[4], val[5] * rs[5],
                            val[6] * rs[6], val[7] * rs[7]);
    float4* op = (float4*)(orow + (size_t)t * HDIM);
    op[0] = lo;
    op[1] = hi;
}

extern "C" void kernel_launch(void* const* d_in, const int* in_sizes, int n_in,
                              void* d_out, int out_size, void* d_ws, size_t ws_size,
                              hipStream_t stream) {
    const float* q    = (const float*)d_in[0];
    const float* k    = (const float*)d_in[1];
    const float* mask = (const float*)d_in[2];
    const float* W    = (const float*)d_in[3];
    const float* b    = (const float*)d_in[4];
    float* out = (float*)d_out;

    hipLaunchKernelGGL(mha_kernel, dim3(2 * NDIM), dim3(BDIM), 0, stream,
                       q, k, mask, W, b, out);
}